// Round 4
// baseline (1253.821 us; speedup 1.0000x reference)
//
#include <hip/hip_runtime.h>
#include <cmath>

#define SLEN 2048

typedef __bf16 bf16x8 __attribute__((ext_vector_type(8)));
typedef __bf16 bf16x2 __attribute__((ext_vector_type(2)));
typedef float  f32x4  __attribute__((ext_vector_type(4)));

__device__ inline bf16x8 zero8() {
    bf16x8 v;
    for (int i = 0; i < 8; i++) v[i] = (__bf16)0.0f;
    return v;
}

// ---------------------------------------------------------------------------
// NT GEMM: C[m,n] = sum_k A[m,k] * B[n,k].  A:[M,K], B:[N,K].
// a32/b32: operand is fp32 in memory (external input) -> convert to bf16 in
// registers during LDS staging.  Otherwise operand is bf16 (intermediate).
// mode 0: C bf16 [M,N] row-major.
// mode 1: C bf16, row stride 3072, col n -> (n>>7)*192 + (n&127).
// mode 2: C fp32 [M,N] row-major (final output -- d_out is float*).
// Tile: BM=BN=128, BK=64; 4 waves, each 64x64 via 4x4 of 16x16x32 MFMA.
// ---------------------------------------------------------------------------
__global__ __launch_bounds__(256, 2)
void gemm_nt(const void* __restrict__ Araw, const void* __restrict__ Braw,
             __bf16* __restrict__ Cb, float* __restrict__ Cf,
             int M, int N, int K, int mode, int a32, int b32) {
    __shared__ __bf16 As[128][72];
    __shared__ __bf16 Bs[128][72];
    const __bf16* Ab = (const __bf16*)Araw;
    const float*  Af = (const float*)Araw;
    const __bf16* Bb = (const __bf16*)Braw;
    const float*  Bf = (const float*)Braw;

    int tid = threadIdx.x;
    int wave = tid >> 6, lane = tid & 63;
    int lane15 = lane & 15, quad = lane >> 4;
    int m0 = blockIdx.x * 128, n0 = blockIdx.y * 128;
    int wm = (wave & 1) * 64, wn = (wave >> 1) * 64;
    f32x4 acc[4][4] = {};
    int ar = tid >> 3;
    int ac = (tid & 7) * 8;

    for (int k0 = 0; k0 < K; k0 += 64) {
#pragma unroll
        for (int i = 0; i < 4; i++) {
            int r = ar + 32 * i;
            size_t idx = (size_t)(m0 + r) * K + k0 + ac;
            bf16x8 va;
            if (a32) {
                float4 u0 = *(const float4*)(Af + idx);
                float4 u1 = *(const float4*)(Af + idx + 4);
                va[0] = (__bf16)u0.x; va[1] = (__bf16)u0.y;
                va[2] = (__bf16)u0.z; va[3] = (__bf16)u0.w;
                va[4] = (__bf16)u1.x; va[5] = (__bf16)u1.y;
                va[6] = (__bf16)u1.z; va[7] = (__bf16)u1.w;
            } else {
                va = *(const bf16x8*)(Ab + idx);
            }
            *(bf16x8*)(&As[r][ac]) = va;
        }
#pragma unroll
        for (int i = 0; i < 4; i++) {
            int r = ar + 32 * i;
            int n = n0 + r;
            bf16x8 vb;
            if (n < N) {
                size_t idx = (size_t)n * K + k0 + ac;
                if (b32) {
                    float4 u0 = *(const float4*)(Bf + idx);
                    float4 u1 = *(const float4*)(Bf + idx + 4);
                    vb[0] = (__bf16)u0.x; vb[1] = (__bf16)u0.y;
                    vb[2] = (__bf16)u0.z; vb[3] = (__bf16)u0.w;
                    vb[4] = (__bf16)u1.x; vb[5] = (__bf16)u1.y;
                    vb[6] = (__bf16)u1.z; vb[7] = (__bf16)u1.w;
                } else {
                    vb = *(const bf16x8*)(Bb + idx);
                }
            } else {
                vb = zero8();
            }
            *(bf16x8*)(&Bs[r][ac]) = vb;
        }
        __syncthreads();
#pragma unroll
        for (int kk = 0; kk < 64; kk += 32) {
            bf16x8 af[4], bfr[4];
#pragma unroll
            for (int mt = 0; mt < 4; mt++)
                af[mt] = *(bf16x8*)(&As[wm + mt * 16 + lane15][kk + quad * 8]);
#pragma unroll
            for (int nt = 0; nt < 4; nt++)
                bfr[nt] = *(bf16x8*)(&Bs[wn + nt * 16 + lane15][kk + quad * 8]);
#pragma unroll
            for (int mt = 0; mt < 4; mt++)
#pragma unroll
                for (int nt = 0; nt < 4; nt++)
                    acc[mt][nt] = __builtin_amdgcn_mfma_f32_16x16x32_bf16(
                        af[mt], bfr[nt], acc[mt][nt], 0, 0, 0);
        }
        __syncthreads();
    }
    // C/D layout (m89/m91-verified): col = lane&15, row = quad*4 + reg
#pragma unroll
    for (int mt = 0; mt < 4; mt++) {
        int row = m0 + wm + mt * 16 + quad * 4;
#pragma unroll
        for (int nt = 0; nt < 4; nt++) {
            int col = n0 + wn + nt * 16 + lane15;
            if (col < N) {
#pragma unroll
                for (int r = 0; r < 4; r++) {
                    float v = acc[mt][nt][r];
                    if (mode == 2)
                        Cf[(size_t)(row + r) * N + col] = v;
                    else if (mode == 1)
                        Cb[(size_t)(row + r) * 3072 + (col >> 7) * 192 + (col & 127)] = (__bf16)v;
                    else
                        Cb[(size_t)(row + r) * N + col] = (__bf16)v;
                }
            }
        }
    }
}

// ---------------------------------------------------------------------------
// RoPE + assemble: rope(q_r) -> q_all[..,128:192], rope(k_r) broadcast ->
// k_all[..,128:192].  One block per token.  Reads our bf16 intermediates.
// ---------------------------------------------------------------------------
__global__ __launch_bounds__(256)
void assemble_rope(const __bf16* __restrict__ q_r, const __bf16* __restrict__ k_r,
                   const int* __restrict__ positions,
                   __bf16* __restrict__ q_all, __bf16* __restrict__ k_all) {
    const float LOG2_10000_OVER_32 = 13.287712379549449f / 32.0f;
    int token = blockIdx.x;
    int s = token & (SLEN - 1);
    int tid = threadIdx.x;
    float p = (float)positions[s];
    __shared__ float krr[64];
    if (tid < 32) {
        float inv = exp2f(-(float)tid * LOG2_10000_OVER_32);
        float ang = p * inv;
        float sn, cs;
        sincosf(ang, &sn, &cs);
        float t1 = (float)k_r[(size_t)token * 64 + tid];
        float t2 = (float)k_r[(size_t)token * 64 + 32 + tid];
        krr[tid]      = t1 * cs - t2 * sn;
        krr[tid + 32] = t2 * cs + t1 * sn;
    }
    __syncthreads();
    for (int t = tid; t < 512; t += 256) {
        int hh = t >> 5, i = t & 31;
        float inv = exp2f(-(float)i * LOG2_10000_OVER_32);
        float ang = p * inv;
        float sn, cs;
        sincosf(ang, &sn, &cs);
        size_t base = (size_t)token * 1024 + hh * 64;
        float t1 = (float)q_r[base + i];
        float t2 = (float)q_r[base + 32 + i];
        size_t ob = (size_t)token * 3072 + hh * 192 + 128;
        q_all[ob + i]      = (__bf16)(t1 * cs - t2 * sn);
        q_all[ob + 32 + i] = (__bf16)(t2 * cs + t1 * sn);
    }
    for (int t = tid; t < 1024; t += 256) {
        int hh = t >> 6, i = t & 63;
        k_all[(size_t)token * 3072 + hh * 192 + 128 + i] = (__bf16)krr[i];
    }
}

// ---------------------------------------------------------------------------
// Causal flash attention.  Q,K: [B,S,H,192]; V: [B,S,H,128].
// Block = (q_tile 64, h, b); 4 waves x 16 Q rows each.
// Vt XOR chunk swizzle: V[n][j] stored at Vt[j][((n>>3)^((j>>3)&7))*8 + (n&7)].
// ---------------------------------------------------------------------------
__global__ __launch_bounds__(256, 2)
void mla_attn(const __bf16* __restrict__ Q, const __bf16* __restrict__ K,
              const __bf16* __restrict__ V, __bf16* __restrict__ O,
              float scale_l2) {
    __shared__ __bf16 Ks[64][200];
    __shared__ __bf16 Vt[128][64];
    __shared__ __bf16 Ps[4][16][72];
    int tid = threadIdx.x, wave = tid >> 6, lane = tid & 63;
    int lane15 = lane & 15, quad = lane >> 4;
    int q0 = blockIdx.x * 64;
    int h = blockIdx.y, b = blockIdx.z;
    const __bf16* Qb = Q + (size_t)b * SLEN * 3072 + h * 192;
    const __bf16* Kb = K + (size_t)b * SLEN * 3072 + h * 192;
    const __bf16* Vb = V + (size_t)b * SLEN * 2048 + h * 128;

    bf16x8 qf[6];
    int qrow = q0 + wave * 16 + lane15;
#pragma unroll
    for (int kk = 0; kk < 6; kk++)
        qf[kk] = *(const bf16x8*)(Qb + (size_t)qrow * 3072 + kk * 32 + quad * 8);

    f32x4 o_acc[8] = {};
    float m_i[4], l_i[4];
#pragma unroll
    for (int r = 0; r < 4; r++) { m_i[r] = -3.0e38f; l_i[r] = 0.0f; }

    for (int j0 = 0; j0 <= q0; j0 += 64) {
#pragma unroll
        for (int i = 0; i < 6; i++) {
            int c = tid + 256 * i;
            int r = c / 24, cc = (c % 24) * 8;
            *(bf16x8*)(&Ks[r][cc]) =
                *(const bf16x8*)(Kb + (size_t)(j0 + r) * 3072 + cc);
        }
#pragma unroll
        for (int i = 0; i < 2; i++) {
            int c = tid + 256 * i;
            int rp = c >> 4;
            int cc = c & 15;
            int colv = cc * 8;
            bf16x8 a0 = *(const bf16x8*)(Vb + (size_t)(j0 + 2 * rp) * 2048 + colv);
            bf16x8 a1 = *(const bf16x8*)(Vb + (size_t)(j0 + 2 * rp + 1) * 2048 + colv);
            int cph = ((rp >> 2) ^ (cc & 7)) * 8 + 2 * (rp & 3);
#pragma unroll
            for (int e = 0; e < 8; e++) {
                bf16x2 pr;
                pr[0] = a0[e];
                pr[1] = a1[e];
                *(bf16x2*)(&Vt[colv + e][cph]) = pr;
            }
        }
        __syncthreads();

        f32x4 sacc[4] = {};
#pragma unroll
        for (int kk = 0; kk < 6; kk++) {
#pragma unroll
            for (int nt = 0; nt < 4; nt++) {
                bf16x8 kf = *(bf16x8*)(&Ks[nt * 16 + lane15][kk * 32 + quad * 8]);
                sacc[nt] = __builtin_amdgcn_mfma_f32_16x16x32_bf16(
                    qf[kk], kf, sacc[nt], 0, 0, 0);
            }
        }

        bool diag = (j0 == q0);
        float sv[4][4];
#pragma unroll
        for (int nt = 0; nt < 4; nt++) {
            int colg = j0 + nt * 16 + lane15;
#pragma unroll
            for (int r = 0; r < 4; r++) {
                float t = sacc[nt][r] * scale_l2;
                int rowg = q0 + wave * 16 + quad * 4 + r;
                if (diag && colg > rowg) t = -3.0e38f;
                sv[nt][r] = t;
            }
        }
#pragma unroll
        for (int r = 0; r < 4; r++) {
            float mx = fmaxf(fmaxf(sv[0][r], sv[1][r]), fmaxf(sv[2][r], sv[3][r]));
#pragma unroll
            for (int d = 8; d >= 1; d >>= 1) mx = fmaxf(mx, __shfl_xor(mx, d));
            float mn = fmaxf(m_i[r], mx);
            float alpha = exp2f(m_i[r] - mn);
            m_i[r] = mn;
            float rs = 0.0f;
#pragma unroll
            for (int nt = 0; nt < 4; nt++) {
                float pp = exp2f(sv[nt][r] - mn);
                Ps[wave][quad * 4 + r][nt * 16 + lane15] = (__bf16)pp;
                rs += pp;
            }
#pragma unroll
            for (int d = 8; d >= 1; d >>= 1) rs += __shfl_xor(rs, d);
            l_i[r] = l_i[r] * alpha + rs;
#pragma unroll
            for (int nt = 0; nt < 8; nt++) o_acc[nt][r] *= alpha;
        }

#pragma unroll
        for (int ks = 0; ks < 2; ks++) {
            bf16x8 pf = *(bf16x8*)(&Ps[wave][lane15][ks * 32 + quad * 8]);
#pragma unroll
            for (int nt = 0; nt < 8; nt++) {
                int nn = nt * 16 + lane15;
                int cph = ((ks * 4 + quad) ^ ((nn >> 3) & 7)) * 8;
                bf16x8 vf = *(bf16x8*)(&Vt[nn][cph]);
                o_acc[nt] = __builtin_amdgcn_mfma_f32_16x16x32_bf16(
                    pf, vf, o_acc[nt], 0, 0, 0);
            }
        }
        __syncthreads();
    }

    int token = b * SLEN + q0 + wave * 16 + quad * 4;
#pragma unroll
    for (int r = 0; r < 4; r++) {
        float inv_l = 1.0f / l_i[r];
#pragma unroll
        for (int nt = 0; nt < 8; nt++) {
            O[(size_t)(token + r) * 2048 + h * 128 + nt * 16 + lane15] =
                (__bf16)(o_acc[nt][r] * inv_l);
        }
    }
}

// ---------------------------------------------------------------------------
extern "C" void kernel_launch(void* const* d_in, const int* in_sizes, int n_in,
                              void* d_out, int out_size, void* d_ws, size_t ws_size,
                              hipStream_t stream) {
    (void)in_sizes; (void)n_in; (void)out_size; (void)ws_size;
    const void* x        = d_in[0];   // fp32 [4096,2048]
    const int*  pos      = (const int*)d_in[1];
    const void* Wq_down  = d_in[2];   // fp32 [1536,2048]
    const void* Wq_up    = d_in[3];   // fp32 [2048,1536]
    const void* Wq_rope  = d_in[4];   // fp32 [1024,1536]
    const void* Wkv_down = d_in[5];   // fp32 [512,2048]
    const void* Wk_up    = d_in[6];   // fp32 [2048,512]
    const void* Wv_up    = d_in[7];   // fp32 [2048,512]
    const void* Wk_rope  = d_in[8];   // fp32 [64,2048]
    const void* Wo       = d_in[9];   // fp32 [2048,2048]
    float* out = (float*)d_out;       // fp32 [4096,2048] (reference output dtype)

    char* ws = (char*)d_ws;
    size_t off = 0;
    auto alloc = [&](size_t bytes) {
        char* p = ws + off;
        off += (bytes + 255) & ~(size_t)255;
        return p;
    };
    __bf16* c_q    = (__bf16*)alloc(4096ull * 1536 * 2);   // dead after q_r gemm
    __bf16* c_kv   = (__bf16*)alloc(4096ull * 512 * 2);    // dead after v gemm
    __bf16* q_r    = (__bf16*)alloc(4096ull * 1024 * 2);
    __bf16* k_r    = (__bf16*)alloc(4096ull * 64 * 2);
    __bf16* v_all  = (__bf16*)alloc(4096ull * 2048 * 2);
    __bf16* q_all  = (__bf16*)alloc(4096ull * 3072 * 2);
    __bf16* k_all  = (__bf16*)alloc(4096ull * 3072 * 2);
    // attn_o (16.78 MB) overlays c_q+c_kv (16.78 MB): all c_q/c_kv consumers
    // run before mla_attn writes it.  Peak ws ~93 MB.
    __bf16* attn_o = (__bf16*)c_q;

    const float scale_l2 = 1.4426950408889634f / sqrtf(192.0f);  // exp2-domain
    dim3 blk(256);

    gemm_nt<<<dim3(32, 12), blk, 0, stream>>>(x, Wq_down, c_q, nullptr, 4096, 1536, 2048, 0, 1, 1);
    gemm_nt<<<dim3(32, 4),  blk, 0, stream>>>(x, Wkv_down, c_kv, nullptr, 4096, 512, 2048, 0, 1, 1);
    gemm_nt<<<dim3(32, 1),  blk, 0, stream>>>(x, Wk_rope, k_r, nullptr, 4096, 64, 2048, 0, 1, 1);
    gemm_nt<<<dim3(32, 16), blk, 0, stream>>>(c_q, Wq_up, q_all, nullptr, 4096, 2048, 1536, 1, 0, 1);
    gemm_nt<<<dim3(32, 8),  blk, 0, stream>>>(c_q, Wq_rope, q_r, nullptr, 4096, 1024, 1536, 0, 0, 1);
    gemm_nt<<<dim3(32, 16), blk, 0, stream>>>(c_kv, Wk_up, k_all, nullptr, 4096, 2048, 512, 1, 0, 1);
    gemm_nt<<<dim3(32, 16), blk, 0, stream>>>(c_kv, Wv_up, v_all, nullptr, 4096, 2048, 512, 0, 0, 1);
    assemble_rope<<<dim3(4096), blk, 0, stream>>>(q_r, k_r, pos, q_all, k_all);
    mla_attn<<<dim3(32, 16, 2), blk, 0, stream>>>(q_all, k_all, v_all, attn_o, scale_l2);
    gemm_nt<<<dim3(32, 16), blk, 0, stream>>>(attn_o, Wo, nullptr, out, 4096, 2048, 2048, 2, 0, 1);
}

// Round 5
// 565.733 us; speedup vs baseline: 2.2163x; 2.2163x over previous
//
#include <hip/hip_runtime.h>
#include <cmath>

#define SLEN 2048

typedef __bf16 bf16x8 __attribute__((ext_vector_type(8)));
typedef float  f32x4  __attribute__((ext_vector_type(4)));

// async global->LDS, 16B per lane. HW scatter: lds_base (wave-uniform) + lane*16.
// AS casts via uintptr per CK convention (LDS aperture low 32 bits = offset).
__device__ inline void gld16(const void* g, void* l) {
    __builtin_amdgcn_global_load_lds(
        (const __attribute__((address_space(1))) void*)(uintptr_t)g,
        (__attribute__((address_space(3))) void*)(unsigned)(uintptr_t)l, 16, 0, 0);
}

// ---------------------------------------------------------------------------
// fp32 -> bf16 bulk convert (one-time; enables global_load_lds in all GEMMs)
// ---------------------------------------------------------------------------
__global__ __launch_bounds__(256)
void f32_to_bf16(const float* __restrict__ s, __bf16* __restrict__ d, long n) {
    long i = ((long)blockIdx.x * 256 + threadIdx.x) * 8;
    if (i >= n) return;
    float4 a = *(const float4*)(s + i);
    float4 b = *(const float4*)(s + i + 4);
    bf16x8 o;
    o[0] = (__bf16)a.x; o[1] = (__bf16)a.y; o[2] = (__bf16)a.z; o[3] = (__bf16)a.w;
    o[4] = (__bf16)b.x; o[5] = (__bf16)b.y; o[6] = (__bf16)b.z; o[7] = (__bf16)b.w;
    *(bf16x8*)(d + i) = o;
}

// ---------------------------------------------------------------------------
// NT GEMM, m97 structure: BM=BN=128, BK=64, 4 waves, 16x16x32 MFMA.
// LDS unpadded (row stride 64 bf16 = 128B), 16B-chunk XOR swizzle:
//   LDS slot (r, c) holds global chunk c ^ (r&7)  ->  frag ds_read_b128 at
//   structural-minimum bank occupancy; staging via global_load_lds (per-lane
//   global addr supplies the swizzle, LDS dest is uniform+lane*16).
// Epilogue modes:
//  0: C bf16 [M,N] row-major
//  1: C bf16, row stride 3072, col n -> (n>>7)*192 + (n&127)   (q/k nope part)
//  2: C fp32 [M,N] row-major (final output)
//  3: C bf16 transposed V: addr = (col*2 + b)*2048 + s, token=row, b=row>>11
//  4: fused RoPE for q: col=h*64+i -> q_all[tok*3072 + h*192 + 128 + {i,i+32}]
//  5: fused RoPE for k (N=64) + broadcast to 16 heads in k_all
// ---------------------------------------------------------------------------
__global__ __launch_bounds__(256, 2)
void gemm_nt(const __bf16* __restrict__ A, const __bf16* __restrict__ B,
             __bf16* __restrict__ Cb, float* __restrict__ Cf,
             const int* __restrict__ positions,
             int M, int N, int K, int mode) {
    __shared__ __bf16 As[128 * 64];
    __shared__ __bf16 Bs[128 * 64];
    int tid = threadIdx.x;
    int wave = tid >> 6, lane = tid & 63;
    int lane15 = lane & 15, quad = lane >> 4;
    int ri = lane >> 3, ci = lane & 7;           // staging: local row / chunk
    int cg = ci ^ ri;                            // swizzled global chunk
    int m0 = blockIdx.x * 128, n0 = blockIdx.y * 128;
    int wm = (wave & 1) * 64, wn = (wave >> 1) * 64;
    f32x4 acc[4][4] = {};

    for (int k0 = 0; k0 < K; k0 += 64) {
#pragma unroll
        for (int t = 0; t < 4; t++) {
            int rr = wave * 32 + t * 8;          // uniform row base of this instr
            int r = rr + ri;
            gld16(A + (size_t)(m0 + r) * K + k0 + cg * 8, As + rr * 64);
            int br = n0 + r; if (br > N - 1) br = N - 1;   // clamp (stores guarded)
            gld16(B + (size_t)br * K + k0 + cg * 8, Bs + rr * 64);
        }
        __syncthreads();
#pragma unroll
        for (int kk = 0; kk < 64; kk += 32) {
            int jb = kk >> 3;                    // 0 or 4
            bf16x8 af[4], bfr[4];
#pragma unroll
            for (int mt = 0; mt < 4; mt++) {
                int rA = wm + mt * 16 + lane15;
                af[mt] = *(bf16x8*)(As + rA * 64 + (((jb + quad) ^ (rA & 7)) << 3));
            }
#pragma unroll
            for (int nt = 0; nt < 4; nt++) {
                int rB = wn + nt * 16 + lane15;
                bfr[nt] = *(bf16x8*)(Bs + rB * 64 + (((jb + quad) ^ (rB & 7)) << 3));
            }
#pragma unroll
            for (int mt = 0; mt < 4; mt++)
#pragma unroll
                for (int nt = 0; nt < 4; nt++)
                    acc[mt][nt] = __builtin_amdgcn_mfma_f32_16x16x32_bf16(
                        af[mt], bfr[nt], acc[mt][nt], 0, 0, 0);
        }
        __syncthreads();
    }

    const float KLOG = 13.287712379549449f / 32.0f;  // log2(10000)/32
    if (mode == 4) {
        // q RoPE: pair (nt, nt+2) = (i, i+32) within one head
#pragma unroll
        for (int mt = 0; mt < 4; mt++) {
            int row = m0 + wm + mt * 16 + quad * 4;
#pragma unroll
            for (int nt = 0; nt < 2; nt++) {
                int col = n0 + wn + nt * 16 + lane15;
                int hh = col >> 6, i = col & 63;          // i in 0..31
                float inv = exp2f(-(float)i * KLOG);
#pragma unroll
                for (int r = 0; r < 4; r++) {
                    int tok = row + r;
                    float p = (float)positions[tok & (SLEN - 1)];
                    float sn, cs; sincosf(p * inv, &sn, &cs);
                    float t1 = acc[mt][nt][r], t2 = acc[mt][nt + 2][r];
                    size_t ob = (size_t)tok * 3072 + hh * 192 + 128;
                    Cb[ob + i]      = (__bf16)(t1 * cs - t2 * sn);
                    Cb[ob + 32 + i] = (__bf16)(t2 * cs + t1 * sn);
                }
            }
        }
        return;
    }
    if (mode == 5) {
        // k RoPE (N=64): waves with wn==0 hold all valid cols; broadcast 16 heads
        if (wn == 0) {
#pragma unroll
            for (int mt = 0; mt < 4; mt++) {
                int row = m0 + wm + mt * 16 + quad * 4;
#pragma unroll
                for (int nt = 0; nt < 2; nt++) {
                    int i = nt * 16 + lane15;             // 0..31
                    float inv = exp2f(-(float)i * KLOG);
#pragma unroll
                    for (int r = 0; r < 4; r++) {
                        int tok = row + r;
                        float p = (float)positions[tok & (SLEN - 1)];
                        float sn, cs; sincosf(p * inv, &sn, &cs);
                        float t1 = acc[mt][nt][r], t2 = acc[mt][nt + 2][r];
                        float rot1 = t1 * cs - t2 * sn;
                        float rot2 = t2 * cs + t1 * sn;
                        size_t ob = (size_t)tok * 3072 + 128;
#pragma unroll
                        for (int hh = 0; hh < 16; hh++) {
                            Cb[ob + hh * 192 + i]      = (__bf16)rot1;
                            Cb[ob + hh * 192 + 32 + i] = (__bf16)rot2;
                        }
                    }
                }
            }
        }
        return;
    }
    // modes 0/1/2/3.  C/D layout (m89/m91): col = lane&15, row = quad*4 + reg
#pragma unroll
    for (int mt = 0; mt < 4; mt++) {
        int row = m0 + wm + mt * 16 + quad * 4;
#pragma unroll
        for (int nt = 0; nt < 4; nt++) {
            int col = n0 + wn + nt * 16 + lane15;
            if (col < N) {
#pragma unroll
                for (int r = 0; r < 4; r++) {
                    float v = acc[mt][nt][r];
                    if (mode == 2) {
                        Cf[(size_t)(row + r) * N + col] = v;
                    } else if (mode == 1) {
                        Cb[(size_t)(row + r) * 3072 + (col >> 7) * 192 + (col & 127)] = (__bf16)v;
                    } else if (mode == 3) {
                        int tok = row + r;
                        Cb[((size_t)col * 2 + (tok >> 11)) * 2048 + (tok & 2047)] = (__bf16)v;
                    } else {
                        Cb[(size_t)(row + r) * N + col] = (__bf16)v;
                    }
                }
            }
        }
    }
}

// ---------------------------------------------------------------------------
// Causal flash attention.  Q,K: [B,S,H*192] token-major; Vt: [H*128][2][S]
// (pre-transposed by mode-3 GEMM).  Block = (q-tile pair, h, b); 4 waves x 16
// Q rows.  Pairing (i, 31-i) -> uniform 33 j-iters/block (no causal tail).
// K LDS: 64x192 unpadded, XOR swizzle within 8-chunk groups.
// Vt LDS: 128x64 unpadded, XOR swizzle.  Both staged via global_load_lds.
// ---------------------------------------------------------------------------
__global__ __launch_bounds__(256, 2)
void mla_attn(const __bf16* __restrict__ Q, const __bf16* __restrict__ K,
              const __bf16* __restrict__ Vt, __bf16* __restrict__ O,
              float scale_l2) {
    __shared__ __bf16 Ks[64 * 192];
    __shared__ __bf16 Vs[128 * 64];
    __shared__ __bf16 Ps[4][16][72];
    int tid = threadIdx.x, wave = tid >> 6, lane = tid & 63;
    int lane15 = lane & 15, quad = lane >> 4;
    int h = blockIdx.y, b = blockIdx.z;
    const __bf16* Qb  = Q + (size_t)b * SLEN * 3072 + h * 192;
    const __bf16* Kb  = K + (size_t)b * SLEN * 3072 + h * 192;
    const __bf16* vtb = Vt + ((size_t)(h * 128) * 2 + b) * 2048;

    for (int half = 0; half < 2; half++) {
        int qt = half ? (31 - blockIdx.x) : blockIdx.x;
        int q0 = qt * 64;

        bf16x8 qf[6];
        int qrow = q0 + wave * 16 + lane15;
#pragma unroll
        for (int kk = 0; kk < 6; kk++)
            qf[kk] = *(const bf16x8*)(Qb + (size_t)qrow * 3072 + kk * 32 + quad * 8);

        f32x4 o_acc[8] = {};
        float m_i[4], l_i[4];
#pragma unroll
        for (int r = 0; r < 4; r++) { m_i[r] = -3.0e38f; l_i[r] = 0.0f; }

        for (int j0 = 0; j0 <= q0; j0 += 64) {
            // K tile: 1536 16B slots; slot (r,c) <- global chunk in same 8-group
#pragma unroll
            for (int t = 0; t < 6; t++) {
                int sb = (wave * 6 + t) * 64;
                int slot = sb + lane;
                int r = slot / 24;
                int c = slot - r * 24;
                int cgk = (c & ~7) | ((c & 7) ^ (r & 7));
                gld16(Kb + (size_t)(j0 + r) * 3072 + cgk * 8, Ks + sb * 8);
            }
            // Vt tile: 1024 slots, 8 chunks/row swizzle
#pragma unroll
            for (int t = 0; t < 4; t++) {
                int sb = (wave * 4 + t) * 64;
                int slot = sb + lane;
                int r = slot >> 3, c = slot & 7;
                gld16(vtb + (size_t)r * 4096 + j0 + (c ^ (r & 7)) * 8, Vs + sb * 8);
            }
            __syncthreads();

            // QK^T
            f32x4 sacc[4] = {};
#pragma unroll
            for (int kk = 0; kk < 6; kk++) {
#pragma unroll
                for (int nt = 0; nt < 4; nt++) {
                    int n = nt * 16 + lane15;
                    int j = kk * 4 + quad;
                    int cl = (j & ~7) | ((j & 7) ^ (n & 7));
                    bf16x8 kf = *(bf16x8*)(Ks + n * 192 + cl * 8);
                    sacc[nt] = __builtin_amdgcn_mfma_f32_16x16x32_bf16(
                        qf[kk], kf, sacc[nt], 0, 0, 0);
                }
            }

            bool diag = (j0 == q0);
            float sv[4][4];
#pragma unroll
            for (int nt = 0; nt < 4; nt++) {
                int colg = j0 + nt * 16 + lane15;
#pragma unroll
                for (int r = 0; r < 4; r++) {
                    float t = sacc[nt][r] * scale_l2;       // exp2 domain
                    int rowg = q0 + wave * 16 + quad * 4 + r;
                    if (diag && colg > rowg) t = -3.0e38f;
                    sv[nt][r] = t;
                }
            }
            // online softmax (rows quad*4+r, reduce across 16 lanes)
#pragma unroll
            for (int r = 0; r < 4; r++) {
                float mx = fmaxf(fmaxf(sv[0][r], sv[1][r]), fmaxf(sv[2][r], sv[3][r]));
#pragma unroll
                for (int d = 8; d >= 1; d >>= 1) mx = fmaxf(mx, __shfl_xor(mx, d));
                float mn = fmaxf(m_i[r], mx);
                float alpha = exp2f(m_i[r] - mn);
                m_i[r] = mn;
                float rs = 0.0f;
#pragma unroll
                for (int nt = 0; nt < 4; nt++) {
                    float pp = exp2f(sv[nt][r] - mn);
                    Ps[wave][quad * 4 + r][nt * 16 + lane15] = (__bf16)pp;
                    rs += pp;
                }
#pragma unroll
                for (int d = 8; d >= 1; d >>= 1) rs += __shfl_xor(rs, d);
                l_i[r] = l_i[r] * alpha + rs;
#pragma unroll
                for (int nt = 0; nt < 8; nt++) o_acc[nt][r] *= alpha;
            }

            // PV: P (A-layout via LDS round-trip) x Vt (B-layout, swizzled)
#pragma unroll
            for (int ks = 0; ks < 2; ks++) {
                bf16x8 pf = *(bf16x8*)(&Ps[wave][lane15][ks * 32 + quad * 8]);
#pragma unroll
                for (int nt = 0; nt < 8; nt++) {
                    int nn = nt * 16 + lane15;
                    int j = ks * 4 + quad;
                    bf16x8 vf = *(bf16x8*)(Vs + nn * 64 + (j ^ (nn & 7)) * 8);
                    o_acc[nt] = __builtin_amdgcn_mfma_f32_16x16x32_bf16(
                        pf, vf, o_acc[nt], 0, 0, 0);
                }
            }
            __syncthreads();
        }

        int token = b * SLEN + q0 + wave * 16 + quad * 4;
#pragma unroll
        for (int r = 0; r < 4; r++) {
            float inv_l = 1.0f / l_i[r];
#pragma unroll
            for (int nt = 0; nt < 8; nt++) {
                O[(size_t)(token + r) * 2048 + h * 128 + nt * 16 + lane15] =
                    (__bf16)(o_acc[nt][r] * inv_l);
            }
        }
    }
}

// ---------------------------------------------------------------------------
extern "C" void kernel_launch(void* const* d_in, const int* in_sizes, int n_in,
                              void* d_out, int out_size, void* d_ws, size_t ws_size,
                              hipStream_t stream) {
    (void)in_sizes; (void)n_in; (void)out_size; (void)ws_size;
    const int* pos = (const int*)d_in[1];
    float* out = (float*)d_out;

    char* ws = (char*)d_ws;
    size_t off = 0;
    auto alloc = [&](size_t bytes) {
        char* p = ws + off;
        off += (bytes + 255) & ~(size_t)255;
        return p;
    };
    // bf16 copies of fp32 inputs (required for global_load_lds staging)
    __bf16* x_bf   = (__bf16*)alloc(8388608ull * 2);
    __bf16* Wqd    = (__bf16*)alloc(3145728ull * 2);
    __bf16* Wqu    = (__bf16*)alloc(3145728ull * 2);
    __bf16* Wqr    = (__bf16*)alloc(1572864ull * 2);
    __bf16* Wkvd   = (__bf16*)alloc(1048576ull * 2);
    __bf16* Wku    = (__bf16*)alloc(1048576ull * 2);
    __bf16* Wvu    = (__bf16*)alloc(1048576ull * 2);
    __bf16* Wkr    = (__bf16*)alloc(131072ull * 2);
    __bf16* Wob    = (__bf16*)alloc(4194304ull * 2);
    // intermediates
    __bf16* c_q    = (__bf16*)alloc(4096ull * 1536 * 2);   // dead after q_rope gemm
    __bf16* c_kv   = (__bf16*)alloc(4096ull * 512 * 2);    // dead after v gemm
    __bf16* v_t    = (__bf16*)alloc(4096ull * 2048 * 2);   // [h*128+d][b][s]
    __bf16* q_all  = (__bf16*)alloc(4096ull * 3072 * 2);
    __bf16* k_all  = (__bf16*)alloc(4096ull * 3072 * 2);
    __bf16* attn_o = (__bf16*)c_q;   // overlays c_q+c_kv (16.78 MB), both dead

    const float scale_l2 = 1.4426950408889634f / sqrtf(192.0f);  // exp2-domain
    dim3 blk(256);

    struct { const void* s; __bf16* d; long n; } cv[9] = {
        { d_in[0], x_bf, 8388608 }, { d_in[2], Wqd, 3145728 },
        { d_in[3], Wqu, 3145728 },  { d_in[4], Wqr, 1572864 },
        { d_in[5], Wkvd, 1048576 }, { d_in[6], Wku, 1048576 },
        { d_in[7], Wvu, 1048576 },  { d_in[8], Wkr, 131072 },
        { d_in[9], Wob, 4194304 },
    };
    for (int i = 0; i < 9; i++)
        f32_to_bf16<<<dim3((unsigned)(cv[i].n / 2048)), blk, 0, stream>>>(
            (const float*)cv[i].s, cv[i].d, cv[i].n);

    gemm_nt<<<dim3(32, 12), blk, 0, stream>>>(x_bf, Wqd, c_q,  nullptr, nullptr, 4096, 1536, 2048, 0);
    gemm_nt<<<dim3(32, 4),  blk, 0, stream>>>(x_bf, Wkvd, c_kv, nullptr, nullptr, 4096, 512, 2048, 0);
    gemm_nt<<<dim3(32, 16), blk, 0, stream>>>(c_q, Wqu, q_all, nullptr, nullptr, 4096, 2048, 1536, 1);
    gemm_nt<<<dim3(32, 8),  blk, 0, stream>>>(c_q, Wqr, q_all, nullptr, pos,     4096, 1024, 1536, 4);
    gemm_nt<<<dim3(32, 16), blk, 0, stream>>>(c_kv, Wku, k_all, nullptr, nullptr, 4096, 2048, 512, 1);
    gemm_nt<<<dim3(32, 1),  blk, 0, stream>>>(x_bf, Wkr, k_all, nullptr, pos,     4096, 64, 2048, 5);
    gemm_nt<<<dim3(32, 16), blk, 0, stream>>>(c_kv, Wvu, v_t,   nullptr, nullptr, 4096, 2048, 512, 3);
    mla_attn<<<dim3(16, 16, 2), blk, 0, stream>>>(q_all, k_all, v_t, attn_o, scale_l2);
    gemm_nt<<<dim3(32, 16), blk, 0, stream>>>(attn_o, Wob, nullptr, out, nullptr, 4096, 2048, 2048, 2);
}

// Round 6
// 430.219 us; speedup vs baseline: 2.9144x; 1.3150x over previous
//
#include <hip/hip_runtime.h>
#include <cmath>

#define SLEN 2048

typedef __bf16 bf16x8 __attribute__((ext_vector_type(8)));
typedef float  f32x4  __attribute__((ext_vector_type(4)));

__device__ inline void gld16(const void* g, void* l) {
    __builtin_amdgcn_global_load_lds(
        (const __attribute__((address_space(1))) void*)(uintptr_t)g,
        (__attribute__((address_space(3))) void*)(unsigned)(uintptr_t)l, 16, 0, 0);
}

// ---------------------------------------------------------------------------
// One-launch fp32->bf16 convert of all 9 inputs (segment table by value).
// ---------------------------------------------------------------------------
struct CvArgs {
    const float* src[9];
    __bf16*      dst[9];
    long         cum[10];
};
__global__ __launch_bounds__(256)
void convert_all(CvArgs a) {
    long i8 = ((long)blockIdx.x * 256 + threadIdx.x) * 8;
    if (i8 >= a.cum[9]) return;
    int s = 0;
#pragma unroll
    for (int k = 1; k < 9; k++) if (i8 >= a.cum[k]) s = k;
    long loc = i8 - a.cum[s];
    const float* sp = a.src[s] + loc;
    float4 u0 = *(const float4*)(sp);
    float4 u1 = *(const float4*)(sp + 4);
    bf16x8 o;
    o[0] = (__bf16)u0.x; o[1] = (__bf16)u0.y; o[2] = (__bf16)u0.z; o[3] = (__bf16)u0.w;
    o[4] = (__bf16)u1.x; o[5] = (__bf16)u1.y; o[6] = (__bf16)u1.z; o[7] = (__bf16)u1.w;
    *(bf16x8*)(a.dst[s] + loc) = o;
}

// ---------------------------------------------------------------------------
// NT GEMM, 128x128x64 tiles, 4 waves, global_load_lds + XOR-swizzled LDS.
// Epilogue modes:
//  2: fp32 [M,N] row-major (final output)
//  8: down-proj merged: col<1536 -> c_q; col<2048 -> c_kv; tile n0==2048 ->
//     k-rope (rotate pairs i/i+32, broadcast 16 heads into k_all)
//  9: up-Q merged (scaled by `scale`): col<2048 -> q_all nope scatter;
//     col>=2048 -> q-rope into q_all[...,128:192]
// 10: up-KV merged: col<2048 -> k_all nope scatter; col>=2048 -> V transpose
// ---------------------------------------------------------------------------
struct Outs { __bf16* a; __bf16* b; __bf16* c; float* f; };

__global__ __launch_bounds__(256, 2)
void gemm_nt(const __bf16* __restrict__ A, const __bf16* __restrict__ B,
             Outs o, const int* __restrict__ positions,
             int M, int N, int K, int mode, float scale) {
    __shared__ __bf16 As[128 * 64];
    __shared__ __bf16 Bs[128 * 64];
    int tid = threadIdx.x;
    int wave = tid >> 6, lane = tid & 63;
    int lane15 = lane & 15, quad = lane >> 4;
    int ri = lane >> 3, ci = lane & 7;
    int cg = ci ^ ri;
    int m0 = blockIdx.x * 128, n0 = blockIdx.y * 128;
    int wm = (wave & 1) * 64, wn = (wave >> 1) * 64;
    f32x4 acc[4][4] = {};

    for (int k0 = 0; k0 < K; k0 += 64) {
#pragma unroll
        for (int t = 0; t < 4; t++) {
            int rr = wave * 32 + t * 8;
            int r = rr + ri;
            gld16(A + (size_t)(m0 + r) * K + k0 + cg * 8, As + rr * 64);
            int br = n0 + r; if (br > N - 1) br = N - 1;
            gld16(B + (size_t)br * K + k0 + cg * 8, Bs + rr * 64);
        }
        __syncthreads();
#pragma unroll
        for (int kk = 0; kk < 64; kk += 32) {
            int jb = kk >> 3;
            bf16x8 af[4], bfr[4];
#pragma unroll
            for (int mt = 0; mt < 4; mt++) {
                int rA = wm + mt * 16 + lane15;
                af[mt] = *(bf16x8*)(As + rA * 64 + (((jb + quad) ^ (rA & 7)) << 3));
            }
#pragma unroll
            for (int nt = 0; nt < 4; nt++) {
                int rB = wn + nt * 16 + lane15;
                bfr[nt] = *(bf16x8*)(Bs + rB * 64 + (((jb + quad) ^ (rB & 7)) << 3));
            }
#pragma unroll
            for (int mt = 0; mt < 4; mt++)
#pragma unroll
                for (int nt = 0; nt < 4; nt++)
                    acc[mt][nt] = __builtin_amdgcn_mfma_f32_16x16x32_bf16(
                        af[mt], bfr[nt], acc[mt][nt], 0, 0, 0);
        }
        __syncthreads();
    }

    const float KLOG = 13.287712379549449f / 32.0f;  // log2(10000)/32

    // --- rope tiles -------------------------------------------------------
    if (mode == 8 && n0 == 2048) {                     // k-rope + broadcast
        if (wn == 0) {
#pragma unroll
            for (int mt = 0; mt < 4; mt++) {
                int row = m0 + wm + mt * 16 + quad * 4;
#pragma unroll
                for (int nt = 0; nt < 2; nt++) {
                    int i = nt * 16 + lane15;          // 0..31
                    float inv = exp2f(-(float)i * KLOG);
#pragma unroll
                    for (int r = 0; r < 4; r++) {
                        int tok = row + r;
                        float p = (float)positions[tok & (SLEN - 1)];
                        float sn, cs; sincosf(p * inv, &sn, &cs);
                        float t1 = acc[mt][nt][r], t2 = acc[mt][nt + 2][r];
                        float rot1 = t1 * cs - t2 * sn;
                        float rot2 = t2 * cs + t1 * sn;
                        size_t ob = (size_t)tok * 3072 + 128;
#pragma unroll
                        for (int hh = 0; hh < 16; hh++) {
                            o.c[ob + hh * 192 + i]      = (__bf16)rot1;
                            o.c[ob + hh * 192 + 32 + i] = (__bf16)rot2;
                        }
                    }
                }
            }
        }
        return;
    }
    if (mode == 9 && n0 >= 2048) {                     // q-rope (scaled)
        int hh = (n0 + wn - 2048) >> 6;
#pragma unroll
        for (int mt = 0; mt < 4; mt++) {
            int row = m0 + wm + mt * 16 + quad * 4;
#pragma unroll
            for (int nt = 0; nt < 2; nt++) {
                int i = nt * 16 + lane15;              // 0..31
                float inv = exp2f(-(float)i * KLOG);
#pragma unroll
                for (int r = 0; r < 4; r++) {
                    int tok = row + r;
                    float p = (float)positions[tok & (SLEN - 1)];
                    float sn, cs; sincosf(p * inv, &sn, &cs);
                    float t1 = acc[mt][nt][r], t2 = acc[mt][nt + 2][r];
                    size_t ob = (size_t)tok * 3072 + hh * 192 + 128;
                    o.a[ob + i]      = (__bf16)((t1 * cs - t2 * sn) * scale);
                    o.a[ob + 32 + i] = (__bf16)((t2 * cs + t1 * sn) * scale);
                }
            }
        }
        return;
    }

    // --- generic epilogues ------------------------------------------------
#pragma unroll
    for (int mt = 0; mt < 4; mt++) {
        int row = m0 + wm + mt * 16 + quad * 4;
#pragma unroll
        for (int nt = 0; nt < 4; nt++) {
            int col = n0 + wn + nt * 16 + lane15;
            if (col < N) {
#pragma unroll
                for (int r = 0; r < 4; r++) {
                    float v = acc[mt][nt][r];
                    size_t rw = (size_t)(row + r);
                    if (mode == 2) {
                        o.f[rw * N + col] = v;
                    } else if (mode == 8) {
                        if (col < 1536) o.a[rw * 1536 + col] = (__bf16)v;
                        else            o.b[rw * 512 + col - 1536] = (__bf16)v;
                    } else if (mode == 9) {
                        o.a[rw * 3072 + (col >> 7) * 192 + (col & 127)] =
                            (__bf16)(v * scale);
                    } else {  // 10
                        if (col < 2048)
                            o.a[rw * 3072 + (col >> 7) * 192 + (col & 127)] = (__bf16)v;
                        else {
                            int d = col - 2048;
                            o.b[((size_t)d * 2 + (rw >> 11)) * 2048 + (rw & 2047)] = (__bf16)v;
                        }
                    }
                }
            }
        }
    }
}

// ---------------------------------------------------------------------------
// Causal flash attention, Q-tile 128 (4 waves x 32 q-rows), K/V-tile 64.
// Q pre-scaled (exp2 domain).  Threshold-max online softmax: m only updated
// when tile max exceeds m+24 (fp32 absorbs 2^24 headroom) -> rescale path is
// rare.  Row sums via MFMA against all-ones B fragment (no shuffles).
// qt mapping: consecutive blocks and b-partners get complementary (qt,15-qt)
// -> balanced under both plausible block->CU packings.
// ---------------------------------------------------------------------------
__global__ __launch_bounds__(256, 2)
void mla_attn(const __bf16* __restrict__ Q, const __bf16* __restrict__ K,
              const __bf16* __restrict__ Vt, __bf16* __restrict__ O) {
    __shared__ __bf16 Ks[64 * 192];
    __shared__ __bf16 Vs[128 * 64];
    __shared__ __bf16 Ps[4][32][72];
    int tid = threadIdx.x, wave = tid >> 6, lane = tid & 63;
    int lane15 = lane & 15, quad = lane >> 4;
    int h = blockIdx.y, b = blockIdx.z;
    int x = blockIdx.x;
    int qt0 = (x & 1) ? (x >> 1) : (15 - (x >> 1));
    int qt = b ? (15 - qt0) : qt0;
    int q0 = qt * 128;
    const __bf16* Qb  = Q + (size_t)b * SLEN * 3072 + h * 192;
    const __bf16* Kb  = K + (size_t)b * SLEN * 3072 + h * 192;
    const __bf16* vtb = Vt + ((size_t)(h * 128) * 2 + b) * 2048;

    bf16x8 qf[2][6];
#pragma unroll
    for (int mt = 0; mt < 2; mt++) {
        int qrow = q0 + wave * 32 + mt * 16 + lane15;
#pragma unroll
        for (int kk = 0; kk < 6; kk++)
            qf[mt][kk] = *(const bf16x8*)(Qb + (size_t)qrow * 3072 + kk * 32 + quad * 8);
    }
    bf16x8 ones;
#pragma unroll
    for (int e = 0; e < 8; e++) ones[e] = (__bf16)1.0f;

    f32x4 o_acc[2][8] = {};
    float m_i[2][4], l_i[2][4];
#pragma unroll
    for (int mt = 0; mt < 2; mt++)
#pragma unroll
        for (int r = 0; r < 4; r++) { m_i[mt][r] = -3.0e38f; l_i[mt][r] = 0.0f; }

    for (int j0 = 0; j0 <= q0 + 64; j0 += 64) {
        // stage K (64x192) and V (128x64), swizzled, via global_load_lds
#pragma unroll
        for (int t = 0; t < 6; t++) {
            int sb = (wave * 6 + t) * 64;
            int slot = sb + lane;
            int r = slot / 24;
            int c = slot - r * 24;
            int cgk = (c & ~7) | ((c & 7) ^ (r & 7));
            gld16(Kb + (size_t)(j0 + r) * 3072 + cgk * 8, Ks + sb * 8);
        }
#pragma unroll
        for (int t = 0; t < 4; t++) {
            int sb = (wave * 4 + t) * 64;
            int slot = sb + lane;
            int r = slot >> 3, c = slot & 7;
            gld16(vtb + (size_t)r * 4096 + j0 + (c ^ (r & 7)) * 8, Vs + sb * 8);
        }
        __syncthreads();

        // QK^T: 2 m-tiles x 4 n-tiles
        f32x4 acc[2][4] = {};
#pragma unroll
        for (int kk = 0; kk < 6; kk++) {
#pragma unroll
            for (int nt = 0; nt < 4; nt++) {
                int n = nt * 16 + lane15;
                int j = kk * 4 + quad;
                int cl = (j & ~7) | ((j & 7) ^ (n & 7));
                bf16x8 kf = *(bf16x8*)(Ks + n * 192 + cl * 8);
#pragma unroll
                for (int mt = 0; mt < 2; mt++)
                    acc[mt][nt] = __builtin_amdgcn_mfma_f32_16x16x32_bf16(
                        qf[mt][kk], kf, acc[mt][nt], 0, 0, 0);
            }
        }

        if (j0 >= q0) {  // causal mask (only last two tiles)
#pragma unroll
            for (int mt = 0; mt < 2; mt++) {
                int rowg = q0 + wave * 32 + mt * 16 + quad * 4;
#pragma unroll
                for (int nt = 0; nt < 4; nt++) {
                    int colg = j0 + nt * 16 + lane15;
#pragma unroll
                    for (int r = 0; r < 4; r++)
                        if (colg > rowg + r) acc[mt][nt][r] = -3.0e38f;
                }
            }
        }

        // threshold-max: slow path only when tile max exceeds m+24
        float mx[2][4];
        bool need = false;
#pragma unroll
        for (int mt = 0; mt < 2; mt++)
#pragma unroll
            for (int r = 0; r < 4; r++) {
                float v = fmaxf(fmaxf(acc[mt][0][r], acc[mt][1][r]),
                                fmaxf(acc[mt][2][r], acc[mt][3][r]));
                mx[mt][r] = v;
                need = need || (v > m_i[mt][r] + 24.0f);
            }
        if (__any(need)) {
#pragma unroll
            for (int mt = 0; mt < 2; mt++)
#pragma unroll
                for (int r = 0; r < 4; r++) {
                    float v = mx[mt][r];
#pragma unroll
                    for (int d = 8; d >= 1; d >>= 1) v = fmaxf(v, __shfl_xor(v, d));
                    float mn = fmaxf(m_i[mt][r], v);
                    float alpha = exp2f(m_i[mt][r] - mn);
                    m_i[mt][r] = mn;
                    l_i[mt][r] *= alpha;
#pragma unroll
                    for (int nt = 0; nt < 8; nt++) o_acc[mt][nt][r] *= alpha;
                }
        }

        // P = exp2(acc - m), store to Ps (A-layout round-trip)
#pragma unroll
        for (int mt = 0; mt < 2; mt++)
#pragma unroll
            for (int r = 0; r < 4; r++)
#pragma unroll
                for (int nt = 0; nt < 4; nt++) {
                    float pp = exp2f(acc[mt][nt][r] - m_i[mt][r]);
                    Ps[wave][mt * 16 + quad * 4 + r][nt * 16 + lane15] = (__bf16)pp;
                }

        // PV + row-sum MFMA
        f32x4 rs[2] = {};
#pragma unroll
        for (int ks = 0; ks < 2; ks++) {
            bf16x8 pf[2];
#pragma unroll
            for (int mt = 0; mt < 2; mt++)
                pf[mt] = *(bf16x8*)(&Ps[wave][mt * 16 + lane15][ks * 32 + quad * 8]);
#pragma unroll
            for (int nt = 0; nt < 8; nt++) {
                int nn = nt * 16 + lane15;
                int j = ks * 4 + quad;
                bf16x8 vf = *(bf16x8*)(Vs + nn * 64 + (j ^ (nn & 7)) * 8);
#pragma unroll
                for (int mt = 0; mt < 2; mt++)
                    o_acc[mt][nt] = __builtin_amdgcn_mfma_f32_16x16x32_bf16(
                        pf[mt], vf, o_acc[mt][nt], 0, 0, 0);
            }
#pragma unroll
            for (int mt = 0; mt < 2; mt++)
                rs[mt] = __builtin_amdgcn_mfma_f32_16x16x32_bf16(
                    pf[mt], ones, rs[mt], 0, 0, 0);
        }
#pragma unroll
        for (int mt = 0; mt < 2; mt++)
#pragma unroll
            for (int r = 0; r < 4; r++) l_i[mt][r] += rs[mt][r];
        __syncthreads();
    }

    int tokb = b * SLEN + q0 + wave * 32 + quad * 4;
#pragma unroll
    for (int mt = 0; mt < 2; mt++) {
#pragma unroll
        for (int r = 0; r < 4; r++) {
            float inv_l = 1.0f / l_i[mt][r];
            int tok = tokb + mt * 16 + r;
#pragma unroll
            for (int nt = 0; nt < 8; nt++) {
                O[(size_t)tok * 2048 + h * 128 + nt * 16 + lane15] =
                    (__bf16)(o_acc[mt][nt][r] * inv_l);
            }
        }
    }
}

// ---------------------------------------------------------------------------
extern "C" void kernel_launch(void* const* d_in, const int* in_sizes, int n_in,
                              void* d_out, int out_size, void* d_ws, size_t ws_size,
                              hipStream_t stream) {
    (void)in_sizes; (void)n_in; (void)out_size; (void)ws_size;
    const int* pos = (const int*)d_in[1];
    float* out = (float*)d_out;

    char* ws = (char*)d_ws;
    size_t off = 0;
    auto alloc = [&](size_t bytes) {
        char* p = ws + off;
        off += (bytes + 255) & ~(size_t)255;
        return p;
    };
    __bf16* x_bf  = (__bf16*)alloc(8388608ull * 2);
    __bf16* Wcat1 = (__bf16*)alloc(4325376ull * 2);  // Wqd | Wkvd | Wkr  (K=2048)
    __bf16* Wcat2 = (__bf16*)alloc(4718592ull * 2);  // Wqu | Wqr        (K=1536)
    __bf16* Wcat3 = (__bf16*)alloc(4194304ull * 2);  // Wku | Wvu        (K=512)
    __bf16* Wob   = (__bf16*)alloc(4194304ull * 2);
    __bf16* c_q   = (__bf16*)alloc(4096ull * 1536 * 2);
    __bf16* c_kv  = (__bf16*)alloc(4096ull * 512 * 2);
    __bf16* v_t   = (__bf16*)alloc(4096ull * 2048 * 2);
    __bf16* q_all = (__bf16*)alloc(4096ull * 3072 * 2);
    __bf16* k_all = (__bf16*)alloc(4096ull * 3072 * 2);
    __bf16* attn_o = (__bf16*)c_q;   // overlays c_q+c_kv (exactly 16.78 MB)

    const float scale_l2 = 1.4426950408889634f / sqrtf(192.0f);
    dim3 blk(256);

    CvArgs cv;
    cv.src[0] = (const float*)d_in[0]; cv.dst[0] = x_bf;
    cv.src[1] = (const float*)d_in[2]; cv.dst[1] = Wcat1;
    cv.src[2] = (const float*)d_in[5]; cv.dst[2] = Wcat1 + 3145728;
    cv.src[3] = (const float*)d_in[8]; cv.dst[3] = Wcat1 + 4194304;
    cv.src[4] = (const float*)d_in[3]; cv.dst[4] = Wcat2;
    cv.src[5] = (const float*)d_in[4]; cv.dst[5] = Wcat2 + 3145728;
    cv.src[6] = (const float*)d_in[6]; cv.dst[6] = Wcat3;
    cv.src[7] = (const float*)d_in[7]; cv.dst[7] = Wcat3 + 1048576;
    cv.src[8] = (const float*)d_in[9]; cv.dst[8] = Wob;
    long ns[9] = {8388608, 3145728, 1048576, 131072, 3145728, 1572864,
                  1048576, 1048576, 4194304};
    cv.cum[0] = 0;
    for (int i = 0; i < 9; i++) cv.cum[i + 1] = cv.cum[i] + ns[i];
    convert_all<<<dim3((unsigned)(cv.cum[9] / 2048)), blk, 0, stream>>>(cv);

    Outs o1 = { c_q, c_kv, k_all, nullptr };
    gemm_nt<<<dim3(32, 17), blk, 0, stream>>>(x_bf, Wcat1, o1, pos, 4096, 2112, 2048, 8, 1.0f);
    Outs o2 = { q_all, nullptr, nullptr, nullptr };
    gemm_nt<<<dim3(32, 24), blk, 0, stream>>>(c_q, Wcat2, o2, pos, 4096, 3072, 1536, 9, scale_l2);
    Outs o3 = { k_all, v_t, nullptr, nullptr };
    gemm_nt<<<dim3(32, 32), blk, 0, stream>>>(c_kv, Wcat3, o3, pos, 4096, 4096, 512, 10, 1.0f);
    mla_attn<<<dim3(16, 16, 2), blk, 0, stream>>>(q_all, k_all, v_t, attn_o);
    Outs o4 = { nullptr, nullptr, nullptr, out };
    gemm_nt<<<dim3(32, 16), blk, 0, stream>>>(attn_o, Wob, o4, pos, 4096, 2048, 2048, 2, 1.0f);
}